// Round 8
// baseline (602.846 us; speedup 1.0000x reference)
//
#include <hip/hip_runtime.h>

typedef unsigned short u16;
typedef __attribute__((ext_vector_type(8))) short bf16x8;
typedef __attribute__((ext_vector_type(8))) unsigned short u16x8;
typedef __attribute__((ext_vector_type(4))) float f32x4;
typedef __attribute__((ext_vector_type(4))) _Float16 f16x4;

__device__ __forceinline__ u16 f2bf(float f) {
  union { float f; unsigned u; } v; v.f = f;
  unsigned r = v.u + 0x7fffu + ((v.u >> 16) & 1u);
  return (u16)(r >> 16);
}
__device__ __forceinline__ float bf2f(u16 u) {
  union { unsigned u; float f; } v; v.u = ((unsigned)u) << 16; return v.f;
}

#define GLOBAL_LOAD_LDS16(g, l)                                                \
  __builtin_amdgcn_global_load_lds(                                            \
      (const __attribute__((address_space(1))) void*)(g),                      \
      (__attribute__((address_space(3))) void*)(l), 16, 0, 0)

// m201 phase tail: reads issued above; barrier lets read-issue overlap other
// waves' previous-phase MFMA; then drain LDS, fence (rule #18), MFMA cluster.
#define PHASE_SYNC()                                                            \
  __builtin_amdgcn_s_barrier();                                                 \
  asm volatile("s_waitcnt lgkmcnt(0)" ::: "memory");                            \
  __builtin_amdgcn_sched_barrier(0)

// ---------------------------------------------------------------- rmsnorm ---
__global__ __launch_bounds__(256) void rmsnorm_k(const float* __restrict__ x,
                                                 const float* __restrict__ w,
                                                 u16* __restrict__ out) {
  __shared__ float red[4];
  const int t = threadIdx.x;
  const size_t base = (size_t)blockIdx.x * 2048 + t * 8;
  float4 a = *(const float4*)(x + base);
  float4 b = *(const float4*)(x + base + 4);
  float ss = a.x * a.x + a.y * a.y + a.z * a.z + a.w * a.w +
             b.x * b.x + b.y * b.y + b.z * b.z + b.w * b.w;
#pragma unroll
  for (int o = 32; o; o >>= 1) ss += __shfl_xor(ss, o);
  if ((t & 63) == 0) red[t >> 6] = ss;
  __syncthreads();
  float rs = rsqrtf((red[0] + red[1] + red[2] + red[3]) * (1.0f / 2048.0f) + 1e-6f);
  float4 wa = *(const float4*)(w + t * 8);
  float4 wb = *(const float4*)(w + t * 8 + 4);
  u16x8 o8;
  o8[0] = f2bf(a.x * rs * wa.x); o8[1] = f2bf(a.y * rs * wa.y);
  o8[2] = f2bf(a.z * rs * wa.z); o8[3] = f2bf(a.w * rs * wa.w);
  o8[4] = f2bf(b.x * rs * wb.x); o8[5] = f2bf(b.y * rs * wb.y);
  o8[6] = f2bf(b.z * rs * wb.z); o8[7] = f2bf(b.w * rs * wb.w);
  *(u16x8*)(out + base) = o8;
}

// ------------------------------------------------------------------- rope ---
__global__ __launch_bounds__(256) void rope_k(u16* __restrict__ buf,
                                              const float* __restrict__ cosp,
                                              const float* __restrict__ sinp,
                                              int nh, int total) {
  int i = blockIdx.x * 256 + threadIdx.x;
  if (i >= total) return;
  int d = i & 63;
  int hh = (i >> 6) % nh;
  int row = i / (64 * nh);      // b*2048 + s
  int s = row & 2047;
  u16* p = buf + (size_t)row * (nh * 128) + hh * 128 + d;
  float x1 = bf2f(p[0]), x2 = bf2f(p[64]);
  float c1 = cosp[s * 128 + d], s1 = sinp[s * 128 + d];
  float c2 = cosp[s * 128 + d + 64], s2 = sinp[s * 128 + d + 64];
  p[0]  = f2bf(x1 * c1 - x2 * s1);
  p[64] = f2bf(x2 * c2 + x1 * s2);
}

// rope over combined qkv [4096][3072]: 16 q heads + 4 k heads.
__global__ __launch_bounds__(256) void rope_qkv(u16* __restrict__ buf,
                                                const float* __restrict__ cosp,
                                                const float* __restrict__ sinp) {
  int i = blockIdx.x * 256 + threadIdx.x;   // grid exactly 20480*256
  int d = i & 63;
  int hh = (i >> 6) % 20;
  int row = i / 1280;
  int s = row & 2047;
  int col = (hh < 16) ? hh * 128 + d : 2048 + (hh - 16) * 128 + d;
  u16* p = buf + (size_t)row * 3072 + col;
  float x1 = bf2f(p[0]), x2 = bf2f(p[64]);
  float c1 = cosp[s * 128 + d], s1 = sinp[s * 128 + d];
  float c2 = cosp[s * 128 + d + 64], s2 = sinp[s * 128 + d + 64];
  p[0]  = f2bf(x1 * c1 - x2 * s1);
  p[64] = f2bf(x2 * c2 + x1 * s2);
}

// --------------------------------------------------------- fp32 -> bf16 ----
__global__ __launch_bounds__(256) void cvt_k(const float* __restrict__ s,
                                             u16* __restrict__ d, int n) {
  int stride = gridDim.x * 256 * 8;
  for (int i = (blockIdx.x * 256 + threadIdx.x) * 8; i < n; i += stride) {
    float4 a = *(const float4*)(s + i);
    float4 b = *(const float4*)(s + i + 4);
    u16x8 o;
    o[0] = f2bf(a.x); o[1] = f2bf(a.y); o[2] = f2bf(a.z); o[3] = f2bf(a.w);
    o[4] = f2bf(b.x); o[5] = f2bf(b.y); o[6] = f2bf(b.z); o[7] = f2bf(b.w);
    *(u16x8*)(d + i) = o;
  }
}

// three fp32 sources -> one contiguous bf16 destination (ranges 8-aligned)
__global__ __launch_bounds__(256) void cvt3_k(const float* __restrict__ s0,
                                              const float* __restrict__ s1,
                                              const float* __restrict__ s2,
                                              u16* __restrict__ d,
                                              int n0, int n1, int n2) {
  int total = n0 + n1 + n2;
  int stride = gridDim.x * 256 * 8;
  for (int i = (blockIdx.x * 256 + threadIdx.x) * 8; i < total; i += stride) {
    const float* s; int off;
    if (i < n0)            { s = s0; off = i; }
    else if (i < n0 + n1)  { s = s1; off = i - n0; }
    else                   { s = s2; off = i - n0 - n1; }
    float4 a = *(const float4*)(s + off);
    float4 b = *(const float4*)(s + off + 4);
    u16x8 o;
    o[0] = f2bf(a.x); o[1] = f2bf(a.y); o[2] = f2bf(a.z); o[3] = f2bf(a.w);
    o[4] = f2bf(b.x); o[5] = f2bf(b.y); o[6] = f2bf(b.z); o[7] = f2bf(b.w);
    *(u16x8*)(d + i) = o;
  }
}

// XCD-chunked, column-major tile order: same-XCD blocks share weight panels.
__device__ __forceinline__ void tile_swz(int bid, int nwg, int tm, int& bm, int& bn) {
  int cpx = nwg >> 3;                       // nwg % 8 == 0 for all our grids
  int w = (bid & 7) * cpx + (bid >> 3);     // bijective chunk remap
  bm = w % tm;                              // column-major decompose
  bn = w / tm;
}

// --------------- generic 4-phase pipelined GEMM: 256M x 128N, BK=64 --------
template <int EPI>
__global__ __launch_bounds__(512, 2) void gemm4p(const u16* __restrict__ A,
                                                 const u16* __restrict__ Bw,
                                                 void* Cout, const float* resid,
                                                 int M, int N, int K) {
  const int NK = K >> 6;
  __shared__ u16 lds[49152];          // 2 buf x (A 16384 + B 8192) u16
  const int t = threadIdx.x, lane = t & 63, w = t >> 6;
  const int wm = w >> 2, wn = w & 3;
  const int l15 = lane & 15, lg = lane >> 4;
  int bm, bn;
  tile_swz(blockIdx.x, gridDim.x, M >> 8, bm, bn);

  const int r64 = t >> 3;
  const int gsrc = ((t & 7) ^ (r64 & 7)) * 8;
  const u16* Asrc[4];
#pragma unroll
  for (int u = 0; u < 4; ++u)
    Asrc[u] = A + (size_t)(bm * 256 + u * 64 + r64) * K + gsrc;
  const u16* Bsrc[2];
#pragma unroll
  for (int u = 0; u < 2; ++u)
    Bsrc[u] = Bw + (size_t)(bn * 128 + u * 64 + r64) * K + gsrc;
  const int d0 = t * 8;

#define STG_A4(buf, u, kt)                                                     \
  GLOBAL_LOAD_LDS16(Asrc[u] + (kt) * 64, &lds[(buf) * 24576 + (u) * 4096 + d0])
#define STG_B4(buf, u, kt)                                                     \
  GLOBAL_LOAD_LDS16(Bsrc[u] + (kt) * 64,                                       \
                    &lds[(buf) * 24576 + 16384 + (u) * 4096 + d0])

  const int swz0 = (lg ^ (l15 & 7)) * 8;
  const int swz1 = ((4 + lg) ^ (l15 & 7)) * 8;
  const int abase = (wm * 128 + l15) * 64;
  const int bbase = 16384 + (wn * 32 + l15) * 64;

  f32x4 acc[8][2] = {};
  bf16x8 af[4], bf0[2], bf1[2];

  STG_A4(0, 0, 0); STG_A4(0, 1, 0); STG_A4(0, 2, 0); STG_A4(0, 3, 0);
  STG_B4(0, 0, 0); STG_B4(0, 1, 0);
  STG_B4(1, 0, 1); STG_B4(1, 1, 1);
  asm volatile("s_waitcnt vmcnt(2)" ::: "memory");
  __builtin_amdgcn_s_barrier();

  for (int T = 0; T < NK; ++T) {
    const int bb = (T & 1) * 24576;
    const int nbuf = (T + 1) & 1, cbuf = T & 1;
    // ---------------- P0: mh=0, ks=0 ----------------
#pragma unroll
    for (int i = 0; i < 4; ++i)
      af[i] = *(const bf16x8*)&lds[bb + abase + i * 1024 + swz0];
#pragma unroll
    for (int n = 0; n < 2; ++n)
      bf0[n] = *(const bf16x8*)&lds[bb + bbase + n * 1024 + swz0];
    if (T < NK - 1) { STG_A4(nbuf, 0, T + 1); STG_A4(nbuf, 1, T + 1); }
    PHASE_SYNC();
    __builtin_amdgcn_s_setprio(1);
#pragma unroll
    for (int i = 0; i < 4; ++i)
#pragma unroll
      for (int n = 0; n < 2; ++n)
        acc[i][n] = __builtin_amdgcn_mfma_f32_16x16x32_bf16(af[i], bf0[n], acc[i][n], 0, 0, 0);
    __builtin_amdgcn_s_setprio(0);
    __builtin_amdgcn_s_barrier();
    // ---------------- P1: mh=0, ks=1 ----------------
#pragma unroll
    for (int i = 0; i < 4; ++i)
      af[i] = *(const bf16x8*)&lds[bb + abase + i * 1024 + swz1];
#pragma unroll
    for (int n = 0; n < 2; ++n)
      bf1[n] = *(const bf16x8*)&lds[bb + bbase + n * 1024 + swz1];
    if (T < NK - 1) { STG_A4(nbuf, 2, T + 1); STG_A4(nbuf, 3, T + 1); }
    PHASE_SYNC();
    __builtin_amdgcn_s_setprio(1);
#pragma unroll
    for (int i = 0; i < 4; ++i)
#pragma unroll
      for (int n = 0; n < 2; ++n)
        acc[i][n] = __builtin_amdgcn_mfma_f32_16x16x32_bf16(af[i], bf1[n], acc[i][n], 0, 0, 0);
    __builtin_amdgcn_s_setprio(0);
    __builtin_amdgcn_s_barrier();
    // ---------------- P2: mh=1, ks=0 ----------------
#pragma unroll
    for (int i = 0; i < 4; ++i)
      af[i] = *(const bf16x8*)&lds[bb + abase + (4 + i) * 1024 + swz0];
    if (T < NK - 2) STG_B4(cbuf, 0, T + 2);
    PHASE_SYNC();
    __builtin_amdgcn_s_setprio(1);
#pragma unroll
    for (int i = 0; i < 4; ++i)
#pragma unroll
      for (int n = 0; n < 2; ++n)
        acc[4 + i][n] = __builtin_amdgcn_mfma_f32_16x16x32_bf16(af[i], bf0[n], acc[4 + i][n], 0, 0, 0);
    __builtin_amdgcn_s_setprio(0);
    __builtin_amdgcn_s_barrier();
    // ---------------- P3: mh=1, ks=1 ----------------
#pragma unroll
    for (int i = 0; i < 4; ++i)
      af[i] = *(const bf16x8*)&lds[bb + abase + (4 + i) * 1024 + swz1];
    if (T < NK - 2) STG_B4(cbuf, 1, T + 2);
    PHASE_SYNC();
    __builtin_amdgcn_s_setprio(1);
#pragma unroll
    for (int i = 0; i < 4; ++i)
#pragma unroll
      for (int n = 0; n < 2; ++n)
        acc[4 + i][n] = __builtin_amdgcn_mfma_f32_16x16x32_bf16(af[i], bf1[n], acc[4 + i][n], 0, 0, 0);
    __builtin_amdgcn_s_setprio(0);
    if (T < NK - 2) asm volatile("s_waitcnt vmcnt(2)" ::: "memory");
    else            asm volatile("s_waitcnt vmcnt(0)" ::: "memory");
    __builtin_amdgcn_s_barrier();
  }
#undef STG_A4
#undef STG_B4

#pragma unroll
  for (int mf = 0; mf < 8; ++mf)
#pragma unroll
    for (int nf = 0; nf < 2; ++nf)
#pragma unroll
      for (int r = 0; r < 4; ++r) {
        int row = bm * 256 + wm * 128 + mf * 16 + lg * 4 + r;
        int col = bn * 128 + wn * 32 + nf * 16 + l15;
        size_t idx = (size_t)row * N + col;
        if (EPI == 0)
          ((u16*)Cout)[idx] = f2bf(acc[mf][nf][r]);
        else
          ((float*)Cout)[idx] = resid[idx] + acc[mf][nf][r];
      }
}

// ---------------- fused gate/up: 4-phase pipelined 256x(128g+128u) ---------
__global__ __launch_bounds__(512, 2) void gu256(const u16* __restrict__ A,
                                                const u16* __restrict__ Wg,
                                                const u16* __restrict__ Wu,
                                                u16* __restrict__ G) {
  constexpr int KD = 2048, NK = 32;
  __shared__ u16 lds[65536];          // 2 buf x (A 16384 + B 16384) u16
  const int t = threadIdx.x, lane = t & 63, w = t >> 6;
  const int wm = w >> 2, wn = w & 3;
  const int l15 = lane & 15, lg = lane >> 4;
  int bm, bn;
  tile_swz(blockIdx.x, gridDim.x, 16, bm, bn);   // grid 704 = 16(M) x 44(N)

  const int l8 = lane >> 3, g8 = lane & 7;
  const int gsrc = (g8 ^ l8) * 8;                 // u16 offset
  const u16* Asrc[2][2];
#pragma unroll
  for (int ha = 0; ha < 2; ++ha)
#pragma unroll
    for (int c = 0; c < 2; ++c)
      Asrc[ha][c] = A + (size_t)(bm * 256 + ha * 128 + w * 16 + c * 8 + l8) * KD + gsrc;
  const u16* Wsel = ((w >> 1) & 1) ? Wu : Wg;     // uniform per wave
  const u16* Bsrc[2][2];
#pragma unroll
  for (int hb = 0; hb < 2; ++hb)
#pragma unroll
    for (int c = 0; c < 2; ++c)
      Bsrc[hb][c] = Wsel + (size_t)(bn * 128 + (hb * 2 + (w >> 2)) * 32 +
                                    (w & 1) * 16 + c * 8 + l8) * KD + gsrc;
  const int dst_wl = w * 1024 + lane * 8;

#define STG_A(buf, ha, kt) do {                                                \
    GLOBAL_LOAD_LDS16(Asrc[ha][0] + (kt) * 64,                                 \
                      &lds[(buf) * 32768 + (ha) * 8192 + dst_wl]);             \
    GLOBAL_LOAD_LDS16(Asrc[ha][1] + (kt) * 64,                                 \
                      &lds[(buf) * 32768 + (ha) * 8192 + dst_wl + 512]); } while (0)
#define STG_B(buf, hb, kt) do {                                                \
    GLOBAL_LOAD_LDS16(Bsrc[hb][0] + (kt) * 64,                                 \
                      &lds[(buf) * 32768 + 16384 + (hb) * 8192 + dst_wl]);     \
    GLOBAL_LOAD_LDS16(Bsrc[hb][1] + (kt) * 64,                                 \
                      &lds[(buf) * 32768 + 16384 + (hb) * 8192 + dst_wl + 512]); } while (0)

  const int swz0 = (lg ^ (l15 & 7)) * 8;
  const int swz1 = ((4 + lg) ^ (l15 & 7)) * 8;
  const int abase = (wm * 128 + l15) * 64;
  const int bbase = 16384 + (wn * 64 + l15) * 64;

  f32x4 acc[8][4] = {};
  bf16x8 af[4], bf0[4], bf1[4];

  STG_A(0, 0, 0); STG_A(0, 1, 0);
  STG_B(0, 0, 0); STG_B(0, 1, 0);
  STG_B(1, 0, 1); STG_B(1, 1, 1);
  asm volatile("s_waitcnt vmcnt(4)" ::: "memory");
  __builtin_amdgcn_s_barrier();

  for (int T = 0; T < NK; ++T) {
    const int bb = (T & 1) * 32768;
    const int nbuf = (T + 1) & 1, cbuf = T & 1;
    // P0
#pragma unroll
    for (int i = 0; i < 4; ++i)
      af[i] = *(const bf16x8*)&lds[bb + abase + i * 1024 + swz0];
#pragma unroll
    for (int n = 0; n < 4; ++n)
      bf0[n] = *(const bf16x8*)&lds[bb + bbase + n * 1024 + swz0];
    if (T < NK - 1) STG_A(nbuf, 0, T + 1);
    PHASE_SYNC();
    __builtin_amdgcn_s_setprio(1);
#pragma unroll
    for (int i = 0; i < 4; ++i)
#pragma unroll
      for (int n = 0; n < 4; ++n)
        acc[i][n] = __builtin_amdgcn_mfma_f32_16x16x32_bf16(af[i], bf0[n], acc[i][n], 0, 0, 0);
    __builtin_amdgcn_s_setprio(0);
    __builtin_amdgcn_s_barrier();
    // P1
#pragma unroll
    for (int i = 0; i < 4; ++i)
      af[i] = *(const bf16x8*)&lds[bb + abase + i * 1024 + swz1];
#pragma unroll
    for (int n = 0; n < 4; ++n)
      bf1[n] = *(const bf16x8*)&lds[bb + bbase + n * 1024 + swz1];
    if (T < NK - 1) STG_A(nbuf, 1, T + 1);
    PHASE_SYNC();
    __builtin_amdgcn_s_setprio(1);
#pragma unroll
    for (int i = 0; i < 4; ++i)
#pragma unroll
      for (int n = 0; n < 4; ++n)
        acc[i][n] = __builtin_amdgcn_mfma_f32_16x16x32_bf16(af[i], bf1[n], acc[i][n], 0, 0, 0);
    __builtin_amdgcn_s_setprio(0);
    __builtin_amdgcn_s_barrier();
    // P2
#pragma unroll
    for (int i = 0; i < 4; ++i)
      af[i] = *(const bf16x8*)&lds[bb + abase + (4 + i) * 1024 + swz0];
    if (T < NK - 2) STG_B(cbuf, 0, T + 2);
    PHASE_SYNC();
    __builtin_amdgcn_s_setprio(1);
#pragma unroll
    for (int i = 0; i < 4; ++i)
#pragma unroll
      for (int n = 0; n < 4; ++n)
        acc[4 + i][n] = __builtin_amdgcn_mfma_f32_16x16x32_bf16(af[i], bf0[n], acc[4 + i][n], 0, 0, 0);
    __builtin_amdgcn_s_setprio(0);
    __builtin_amdgcn_s_barrier();
    // P3
#pragma unroll
    for (int i = 0; i < 4; ++i)
      af[i] = *(const bf16x8*)&lds[bb + abase + (4 + i) * 1024 + swz1];
    if (T < NK - 2) STG_B(cbuf, 1, T + 2);
    PHASE_SYNC();
    __builtin_amdgcn_s_setprio(1);
#pragma unroll
    for (int i = 0; i < 4; ++i)
#pragma unroll
      for (int n = 0; n < 4; ++n)
        acc[4 + i][n] = __builtin_amdgcn_mfma_f32_16x16x32_bf16(af[i], bf1[n], acc[4 + i][n], 0, 0, 0);
    __builtin_amdgcn_s_setprio(0);
    if (T < NK - 2) asm volatile("s_waitcnt vmcnt(4)" ::: "memory");
    else            asm volatile("s_waitcnt vmcnt(0)" ::: "memory");
    __builtin_amdgcn_s_barrier();
  }
#undef STG_A
#undef STG_B

  const size_t grow0 = (size_t)(bm * 256 + wm * 128 + lg * 4);
  const int gcol0 = bn * 128 + wn * 32 + l15;
#pragma unroll
  for (int mf = 0; mf < 8; ++mf)
#pragma unroll
    for (int p = 0; p < 2; ++p)
#pragma unroll
      for (int r = 0; r < 4; ++r) {
        float gg = acc[mf][p][r], uu = acc[mf][p + 2][r];
        float sg = gg / (1.0f + __expf(-gg));
        G[(grow0 + mf * 16 + r) * 5632 + gcol0 + p * 16] = f2bf(sg * uu);
      }
}

// ======================= fp32-weight fallback path (round-1, verified) =====
template <int EPI>
__global__ __launch_bounds__(256) void gemm_bt(const u16* __restrict__ A,
                                               const float* __restrict__ Bw,
                                               void* Cout, const float* resid,
                                               int M, int N, int K) {
  __shared__ u16 sA[128 * 32];
  __shared__ u16 sB[128 * 40];
  const int t = threadIdx.x, lane = t & 63, w = t >> 6;
  const int l15 = lane & 15, lg = lane >> 4;
  const int tn = N >> 7;
  const int bm = blockIdx.x / tn, bn = blockIdx.x % tn;
  const int wr = (w >> 1) << 6, wc = (w & 1) << 6;

  const u16* Ag  = A + (size_t)(bm * 128 + (t >> 2)) * K + (t & 3) * 8;
  const u16* Ag2 = Ag + (size_t)64 * K;
  const float* Bg  = Bw + (size_t)(bn * 128 + (t >> 2)) * K + (t & 3) * 8;
  const float* Bg2 = Bg + (size_t)64 * K;
  u16* sBp  = &sB[(t >> 2) * 40 + (t & 3) * 8];
  u16* sBp2 = sBp + 64 * 40;

  f32x4 acc[4][4] = {};

  for (int kt = 0; kt < K; kt += 32) {
    float4 b0 = *(const float4*)(Bg + kt);
    float4 b1 = *(const float4*)(Bg + kt + 4);
    float4 c0 = *(const float4*)(Bg2 + kt);
    float4 c1 = *(const float4*)(Bg2 + kt + 4);
    GLOBAL_LOAD_LDS16(Ag + kt, &sA[t * 8]);
    GLOBAL_LOAD_LDS16(Ag2 + kt, &sA[64 * 32 + t * 8]);
    u16x8 bs;
    bs[0] = f2bf(b0.x); bs[1] = f2bf(b0.y); bs[2] = f2bf(b0.z); bs[3] = f2bf(b0.w);
    bs[4] = f2bf(b1.x); bs[5] = f2bf(b1.y); bs[6] = f2bf(b1.z); bs[7] = f2bf(b1.w);
    *(u16x8*)sBp = bs;
    bs[0] = f2bf(c0.x); bs[1] = f2bf(c0.y); bs[2] = f2bf(c0.z); bs[3] = f2bf(c0.w);
    bs[4] = f2bf(c1.x); bs[5] = f2bf(c1.y); bs[6] = f2bf(c1.z); bs[7] = f2bf(c1.w);
    *(u16x8*)sBp2 = bs;
    __syncthreads();
    bf16x8 af[4], bfr[4];
#pragma unroll
    for (int m = 0; m < 4; ++m)
      af[m] = *(const bf16x8*)&sA[(wr + m * 16 + l15) * 32 + lg * 8];
#pragma unroll
    for (int n = 0; n < 4; ++n)
      bfr[n] = *(const bf16x8*)&sB[(wc + n * 16 + l15) * 40 + lg * 8];
#pragma unroll
    for (int m = 0; m < 4; ++m)
#pragma unroll
      for (int n = 0; n < 4; ++n)
        acc[m][n] = __builtin_amdgcn_mfma_f32_16x16x32_bf16(af[m], bfr[n], acc[m][n], 0, 0, 0);
    __syncthreads();
  }
#pragma unroll
  for (int m = 0; m < 4; ++m)
#pragma unroll
    for (int n = 0; n < 4; ++n)
#pragma unroll
      for (int r = 0; r < 4; ++r) {
        int row = bm * 128 + wr + m * 16 + lg * 4 + r;
        int col = bn * 128 + wc + n * 16 + l15;
        size_t idx = (size_t)row * N + col;
        if (EPI == 0)
          ((u16*)Cout)[idx] = f2bf(acc[m][n][r]);
        else
          ((float*)Cout)[idx] = resid[idx] + acc[m][n][r];
      }
}

__global__ __launch_bounds__(512) void gemm_gateup(const u16* __restrict__ A,
                                                   const float* __restrict__ Wg,
                                                   const float* __restrict__ Wu,
                                                   u16* __restrict__ G) {
  constexpr int N = 5632, K = 2048;
  __shared__ u16 sA[128 * 32];
  __shared__ u16 sB1[128 * 40];
  __shared__ u16 sB2[128 * 40];
  const int t = threadIdx.x, lane = t & 63, w = t >> 6;
  const int l15 = lane & 15, lg = lane >> 4;
  const int bm = blockIdx.x / 44, bn = blockIdx.x % 44;
  const int wr = (w >> 2) << 6, wc = (w & 3) << 5;

  const u16* Ag = A + (size_t)(bm * 128 + (t >> 2)) * K + (t & 3) * 8;
  const float* Bg1 = Wg + (size_t)(bn * 128 + (t >> 2)) * K + (t & 3) * 8;
  const float* Bg2 = Wu + (size_t)(bn * 128 + (t >> 2)) * K + (t & 3) * 8;
  const int sboff = (t >> 2) * 40 + (t & 3) * 8;

  f32x4 acc1[4][2] = {};
  f32x4 acc2[4][2] = {};

  for (int kt = 0; kt < K; kt += 32) {
    float4 g0 = *(const float4*)(Bg1 + kt);
    float4 g1 = *(const float4*)(Bg1 + kt + 4);
    float4 u0 = *(const float4*)(Bg2 + kt);
    float4 u1 = *(const float4*)(Bg2 + kt + 4);
    GLOBAL_LOAD_LDS16(Ag + kt, &sA[t * 8]);
    u16x8 bs;
    bs[0] = f2bf(g0.x); bs[1] = f2bf(g0.y); bs[2] = f2bf(g0.z); bs[3] = f2bf(g0.w);
    bs[4] = f2bf(g1.x); bs[5] = f2bf(g1.y); bs[6] = f2bf(g1.z); bs[7] = f2bf(g1.w);
    *(u16x8*)&sB1[sboff] = bs;
    bs[0] = f2bf(u0.x); bs[1] = f2bf(u0.y); bs[2] = f2bf(u0.z); bs[3] = f2bf(u0.w);
    bs[4] = f2bf(u1.x); bs[5] = f2bf(u1.y); bs[6] = f2bf(u1.z); bs[7] = f2bf(u1.w);
    *(u16x8*)&sB2[sboff] = bs;
    __syncthreads();
    bf16x8 af[4], b1f[2], b2f[2];
#pragma unroll
    for (int m = 0; m < 4; ++m)
      af[m] = *(const bf16x8*)&sA[(wr + m * 16 + l15) * 32 + lg * 8];
#pragma unroll
    for (int n = 0; n < 2; ++n) {
      b1f[n] = *(const bf16x8*)&sB1[(wc + n * 16 + l15) * 40 + lg * 8];
      b2f[n] = *(const bf16x8*)&sB2[(wc + n * 16 + l15) * 40 + lg * 8];
    }
#pragma unroll
    for (int m = 0; m < 4; ++m)
#pragma unroll
      for (int n = 0; n < 2; ++n) {
        acc1[m][n] = __builtin_amdgcn_mfma_f32_16x16x32_bf16(af[m], b1f[n], acc1[m][n], 0, 0, 0);
        acc2[m][n] = __builtin_amdgcn_mfma_f32_16x16x32_bf16(af[m], b2f[n], acc2[m][n], 0, 0, 0);
      }
    __syncthreads();
  }
#pragma unroll
  for (int m = 0; m < 4; ++m)
#pragma unroll
    for (int n = 0; n < 2; ++n)
#pragma unroll
      for (int r = 0; r < 4; ++r) {
        int row = bm * 128 + wr + m * 16 + lg * 4 + r;
        int col = bn * 128 + wc + n * 16 + l15;
        float ga = acc1[m][n][r], uu = acc2[m][n][r];
        float sg = ga / (1.0f + __expf(-ga));
        G[(size_t)row * N + col] = f2bf(sg * uu);
      }
}

// -------------------------------------------------------------- attention ---
__global__ __launch_bounds__(256) void attn_k(const u16* __restrict__ Q,
                                              const u16* __restrict__ K,
                                              const u16* __restrict__ V,
                                              u16* __restrict__ O,
                                              int qstr, int kvstr) {
  const int lane = threadIdx.x & 63;
  const int wid = blockIdx.x * 4 + (threadIdx.x >> 6);
  const int qt = wid & 127;
  const int h = (wid >> 7) & 15;
  const int b = wid >> 11;
  const int q0 = qt << 4;
  const int kvh = h >> 2;
  const int l15 = lane & 15, lg = lane >> 4;

  bf16x8 qf[4];
  {
    const u16* qp = Q + (size_t)((b << 11) + q0 + l15) * qstr + h * 128 + lg * 8;
#pragma unroll
    for (int ds = 0; ds < 4; ++ds) qf[ds] = *(const bf16x8*)(qp + ds * 32);
  }
  float m_run = -1e30f, l_run = 0.0f;
  f32x4 oacc[8];
#pragma unroll
  for (int db = 0; db < 8; ++db) oacc[db] = f32x4{0.f, 0.f, 0.f, 0.f};

  int lo = q0 - 511;
  if (lo < 0) lo = 0;
  for (int kb = (lo & ~15); kb <= q0; kb += 16) {
    f32x4 st = {0.f, 0.f, 0.f, 0.f};
    const u16* kp = K + (size_t)((b << 11) + kb + l15) * kvstr + kvh * 128 + lg * 8;
#pragma unroll
    for (int ds = 0; ds < 4; ++ds)
      st = __builtin_amdgcn_mfma_f32_16x16x32_bf16(*(const bf16x8*)(kp + ds * 32),
                                                   qf[ds], st, 0, 0, 0);
    const int qpos = q0 + l15;
    float pe[4];
    float tmax = -1e30f;
#pragma unroll
    for (int r = 0; r < 4; ++r) {
      int j = kb + lg * 4 + r;
      int d = qpos - j;
      bool ok = (d >= 0) && (d < 512);
      pe[r] = ok ? st[r] * 0.08838834764831845f : -1e30f;
      tmax = fmaxf(tmax, pe[r]);
    }
    tmax = fmaxf(tmax, __shfl_xor(tmax, 16));
    tmax = fmaxf(tmax, __shfl_xor(tmax, 32));
    float m_new = fmaxf(m_run, tmax);
    float corr = __expf(m_run - m_new);
    float psum = 0.0f;
#pragma unroll
    for (int r = 0; r < 4; ++r) {
      float e = (pe[r] > -1e29f) ? __expf(pe[r] - m_new) : 0.0f;
      pe[r] = e;
      psum += e;
    }
    psum += __shfl_xor(psum, 16);
    psum += __shfl_xor(psum, 32);
    l_run = l_run * corr + psum;
    m_run = m_new;

    f16x4 pf;
#pragma unroll
    for (int r = 0; r < 4; ++r) pf[r] = (_Float16)pe[r];

    float f0 = __shfl(corr, lg * 4 + 0);
    float f1 = __shfl(corr, lg * 4 + 1);
    float f2 = __shfl(corr, lg * 4 + 2);
    float f3 = __shfl(corr, lg * 4 + 3);
    const u16* vp = V + (size_t)((b << 11) + kb + lg * 4) * kvstr + kvh * 128 + l15;
#pragma unroll
    for (int db = 0; db < 8; ++db) {
      oacc[db][0] *= f0; oacc[db][1] *= f1; oacc[db][2] *= f2; oacc[db][3] *= f3;
      f16x4 vf;
#pragma unroll
      for (int e = 0; e < 4; ++e)
        vf[e] = (_Float16)bf2f(vp[(size_t)e * kvstr + db * 16]);
      oacc[db] = __builtin_amdgcn_mfma_f32_16x16x16f16(pf, vf, oacc[db], 0, 0, 0);
    }
  }
  float inv = 1.0f / l_run;
  float g0 = __shfl(inv, lg * 4 + 0);
  float g1 = __shfl(inv, lg * 4 + 1);
  float g2 = __shfl(inv, lg * 4 + 2);
  float g3 = __shfl(inv, lg * 4 + 3);
  u16* op = O + (size_t)((b << 11) + q0 + lg * 4) * 2048 + h * 128 + l15;
#pragma unroll
  for (int db = 0; db < 8; ++db) {
    op[0 * 2048 + db * 16] = f2bf(oacc[db][0] * g0);
    op[1 * 2048 + db * 16] = f2bf(oacc[db][1] * g1);
    op[2 * 2048 + db * 16] = f2bf(oacc[db][2] * g2);
    op[3 * 2048 + db * 16] = f2bf(oacc[db][3] * g3);
  }
}

// ----------------------------------------------------------------- launch ---
extern "C" void kernel_launch(void* const* d_in, const int* in_sizes, int n_in,
                              void* d_out, int out_size, void* d_ws, size_t ws_size,
                              hipStream_t stream) {
  const float* x    = (const float*)d_in[0];
  const float* cosp = (const float*)d_in[1];
  const float* sinp = (const float*)d_in[2];
  const float* ln1  = (const float*)d_in[3];
  const float* ln2  = (const float*)d_in[4];
  const float* wq   = (const float*)d_in[5];
  const float* wk   = (const float*)d_in[6];
  const float* wv   = (const float*)d_in[7];
  const float* wo   = (const float*)d_in[8];
  const float* wg   = (const float*)d_in[9];
  const float* wu   = (const float*)d_in[10];
  const float* wd   = (const float*)d_in[11];
  float* out = (float*)d_out;

  const size_t SZ_HQ  = 8388608;   // 4096*2048
  const size_t SZ_KV  = 2097152;   // 4096*512
  const size_t SZ_QKV = 12582912;  // 4096*3072
  const size_t SZ_G   = 23068672;  // 4096*5632
  const size_t SZ_WB  = 23068672;  // max bf16 weight residency (wg+wu)
  const size_t need_old = (SZ_HQ * 3 + SZ_KV * 2 + SZ_G) * 2;            // 100 MiB
  const size_t need_new = (SZ_HQ * 2 + SZ_QKV + SZ_G + SZ_WB) * 2;       // 144 MiB
  if (ws_size < need_old) return;  // clean fail rather than OOB

  if (ws_size >= need_new) {
    // ---- bf16-weight pipelined path ----
    u16* h   = (u16*)d_ws;
    u16* qkv = h + SZ_HQ;               // [4096][3072]: q | k | v
    u16* at  = qkv + SZ_QKV;
    u16* g   = at + SZ_HQ;
    u16* wb  = g + SZ_G;                // reused weight slab
    u16* wqb = wb;                      // 3072x2048 combined qkv weights
    u16* wob = wb;                      // reused after QKV
    u16* wgb = wb;                      // reused: gate (wub contiguous)
    u16* wdb = wb;                      // reused: down

    rmsnorm_k<<<4096, 256, 0, stream>>>(x, ln1, h);
    cvt3_k<<<2048, 256, 0, stream>>>(wq, wk, wv, wqb, 4194304, 1048576, 1048576);
    gemm4p<0><<<384, 512, 0, stream>>>(h, wqb, qkv, nullptr, 4096, 3072, 2048);
    rope_qkv<<<20480, 256, 0, stream>>>(qkv, cosp, sinp);
    attn_k<<<1024, 256, 0, stream>>>(qkv, qkv + 2048, qkv + 2560, at, 3072, 3072);
    cvt_k<<<2048, 256, 0, stream>>>(wo, wob, 4194304);
    gemm4p<1><<<256, 512, 0, stream>>>(at, wob, d_out, x, 4096, 2048, 2048);
    rmsnorm_k<<<4096, 256, 0, stream>>>(out, ln2, h);
    cvt3_k<<<2048, 256, 0, stream>>>(wg, wu, wu, wgb, 11534336, 11534336, 0);
    gu256<<<704, 512, 0, stream>>>(h, wgb, wgb + 11534336, g);
    cvt_k<<<2048, 256, 0, stream>>>(wd, wdb, 11534336);
    gemm4p<1><<<256, 512, 0, stream>>>(g, wdb, d_out, out, 4096, 2048, 5632);
  } else {
    // ---- fp32-weight fallback (round-1 verified) ----
    u16* h  = (u16*)d_ws;
    u16* q  = h + SZ_HQ;
    u16* kk = q + SZ_HQ;
    u16* vv = kk + SZ_KV;
    u16* at = vv + SZ_KV;
    u16* g  = at + SZ_HQ;

    rmsnorm_k<<<4096, 256, 0, stream>>>(x, ln1, h);
    gemm_bt<0><<<512, 256, 0, stream>>>(h, wq, q,  nullptr, 4096, 2048, 2048);
    gemm_bt<0><<<128, 256, 0, stream>>>(h, wk, kk, nullptr, 4096, 512, 2048);
    gemm_bt<0><<<128, 256, 0, stream>>>(h, wv, vv, nullptr, 4096, 512, 2048);
    rope_k<<<16384, 256, 0, stream>>>(q, cosp, sinp, 16, 4194304);
    rope_k<<<4096, 256, 0, stream>>>(kk, cosp, sinp, 4, 1048576);
    attn_k<<<1024, 256, 0, stream>>>(q, kk, vv, at, 2048, 512);
    gemm_bt<1><<<512, 256, 0, stream>>>(at, wo, d_out, x, 4096, 2048, 2048);
    rmsnorm_k<<<4096, 256, 0, stream>>>(out, ln2, h);
    gemm_gateup<<<1408, 512, 0, stream>>>(h, wg, wu, g);
    gemm_bt<1><<<512, 256, 0, stream>>>(g, wd, d_out, out, 4096, 2048, 5632);
  }
}

// Round 9
// 565.414 us; speedup vs baseline: 1.0662x; 1.0662x over previous
//
#include <hip/hip_runtime.h>

typedef unsigned short u16;
typedef __attribute__((ext_vector_type(8))) short bf16x8;
typedef __attribute__((ext_vector_type(8))) unsigned short u16x8;
typedef __attribute__((ext_vector_type(4))) float f32x4;
typedef __attribute__((ext_vector_type(4))) _Float16 f16x4;

__device__ __forceinline__ u16 f2bf(float f) {
  union { float f; unsigned u; } v; v.f = f;
  unsigned r = v.u + 0x7fffu + ((v.u >> 16) & 1u);
  return (u16)(r >> 16);
}
__device__ __forceinline__ float bf2f(u16 u) {
  union { unsigned u; float f; } v; v.u = ((unsigned)u) << 16; return v.f;
}

#define GLOBAL_LOAD_LDS16(g, l)                                                \
  __builtin_amdgcn_global_load_lds(                                            \
      (const __attribute__((address_space(1))) void*)(g),                      \
      (__attribute__((address_space(3))) void*)(l), 16, 0, 0)

// round-7 phase tail (verified faster than pre-barrier variant, r8):
// drain LDS reads, fence against MFMA hoist (rule #18), prioritized MFMA.
#define PHASE_TAIL()                                                           \
  asm volatile("s_waitcnt lgkmcnt(0)" ::: "memory");                           \
  __builtin_amdgcn_sched_barrier(0);                                           \
  __builtin_amdgcn_s_setprio(1)

// ---------------------------------------------------------------- rmsnorm ---
__global__ __launch_bounds__(256) void rmsnorm_k(const float* __restrict__ x,
                                                 const float* __restrict__ w,
                                                 u16* __restrict__ out) {
  __shared__ float red[4];
  const int t = threadIdx.x;
  const size_t base = (size_t)blockIdx.x * 2048 + t * 8;
  float4 a = *(const float4*)(x + base);
  float4 b = *(const float4*)(x + base + 4);
  float ss = a.x * a.x + a.y * a.y + a.z * a.z + a.w * a.w +
             b.x * b.x + b.y * b.y + b.z * b.z + b.w * b.w;
#pragma unroll
  for (int o = 32; o; o >>= 1) ss += __shfl_xor(ss, o);
  if ((t & 63) == 0) red[t >> 6] = ss;
  __syncthreads();
  float rs = rsqrtf((red[0] + red[1] + red[2] + red[3]) * (1.0f / 2048.0f) + 1e-6f);
  float4 wa = *(const float4*)(w + t * 8);
  float4 wb = *(const float4*)(w + t * 8 + 4);
  u16x8 o8;
  o8[0] = f2bf(a.x * rs * wa.x); o8[1] = f2bf(a.y * rs * wa.y);
  o8[2] = f2bf(a.z * rs * wa.z); o8[3] = f2bf(a.w * rs * wa.w);
  o8[4] = f2bf(b.x * rs * wb.x); o8[5] = f2bf(b.y * rs * wb.y);
  o8[6] = f2bf(b.z * rs * wb.z); o8[7] = f2bf(b.w * rs * wb.w);
  *(u16x8*)(out + base) = o8;
}

// ------------------------------------------------------------------- rope ---
__global__ __launch_bounds__(256) void rope_k(u16* __restrict__ buf,
                                              const float* __restrict__ cosp,
                                              const float* __restrict__ sinp,
                                              int nh, int total) {
  int i = blockIdx.x * 256 + threadIdx.x;
  if (i >= total) return;
  int d = i & 63;
  int hh = (i >> 6) % nh;
  int row = i / (64 * nh);      // b*2048 + s
  int s = row & 2047;
  u16* p = buf + (size_t)row * (nh * 128) + hh * 128 + d;
  float x1 = bf2f(p[0]), x2 = bf2f(p[64]);
  float c1 = cosp[s * 128 + d], s1 = sinp[s * 128 + d];
  float c2 = cosp[s * 128 + d + 64], s2 = sinp[s * 128 + d + 64];
  p[0]  = f2bf(x1 * c1 - x2 * s1);
  p[64] = f2bf(x2 * c2 + x1 * s2);
}

// rope over combined qkv [4096][3072]: 16 q heads + 4 k heads.
__global__ __launch_bounds__(256) void rope_qkv(u16* __restrict__ buf,
                                                const float* __restrict__ cosp,
                                                const float* __restrict__ sinp) {
  int i = blockIdx.x * 256 + threadIdx.x;   // grid exactly 20480*256
  int d = i & 63;
  int hh = (i >> 6) % 20;
  int row = i / 1280;
  int s = row & 2047;
  int col = (hh < 16) ? hh * 128 + d : 2048 + (hh - 16) * 128 + d;
  u16* p = buf + (size_t)row * 3072 + col;
  float x1 = bf2f(p[0]), x2 = bf2f(p[64]);
  float c1 = cosp[s * 128 + d], s1 = sinp[s * 128 + d];
  float c2 = cosp[s * 128 + d + 64], s2 = sinp[s * 128 + d + 64];
  p[0]  = f2bf(x1 * c1 - x2 * s1);
  p[64] = f2bf(x2 * c2 + x1 * s2);
}

// --------------------------------------------------------- fp32 -> bf16 ----
__global__ __launch_bounds__(256) void cvt_k(const float* __restrict__ s,
                                             u16* __restrict__ d, int n) {
  int stride = gridDim.x * 256 * 8;
  for (int i = (blockIdx.x * 256 + threadIdx.x) * 8; i < n; i += stride) {
    float4 a = *(const float4*)(s + i);
    float4 b = *(const float4*)(s + i + 4);
    u16x8 o;
    o[0] = f2bf(a.x); o[1] = f2bf(a.y); o[2] = f2bf(a.z); o[3] = f2bf(a.w);
    o[4] = f2bf(b.x); o[5] = f2bf(b.y); o[6] = f2bf(b.z); o[7] = f2bf(b.w);
    *(u16x8*)(d + i) = o;
  }
}

// three fp32 sources -> one contiguous bf16 destination (ranges 8-aligned)
__global__ __launch_bounds__(256) void cvt3_k(const float* __restrict__ s0,
                                              const float* __restrict__ s1,
                                              const float* __restrict__ s2,
                                              u16* __restrict__ d,
                                              int n0, int n1, int n2) {
  int total = n0 + n1 + n2;
  int stride = gridDim.x * 256 * 8;
  for (int i = (blockIdx.x * 256 + threadIdx.x) * 8; i < total; i += stride) {
    const float* s; int off;
    if (i < n0)            { s = s0; off = i; }
    else if (i < n0 + n1)  { s = s1; off = i - n0; }
    else                   { s = s2; off = i - n0 - n1; }
    float4 a = *(const float4*)(s + off);
    float4 b = *(const float4*)(s + off + 4);
    u16x8 o;
    o[0] = f2bf(a.x); o[1] = f2bf(a.y); o[2] = f2bf(a.z); o[3] = f2bf(a.w);
    o[4] = f2bf(b.x); o[5] = f2bf(b.y); o[6] = f2bf(b.z); o[7] = f2bf(b.w);
    *(u16x8*)(d + i) = o;
  }
}

// XCD-chunked, column-major tile order: same-XCD blocks share weight panels.
__device__ __forceinline__ void tile_swz(int bid, int nwg, int tm, int& bm, int& bn) {
  int cpx = nwg >> 3;                       // nwg % 8 == 0 for all our grids
  int w = (bid & 7) * cpx + (bid >> 3);     // bijective chunk remap
  bm = w % tm;                              // column-major decompose
  bn = w / tm;
}

// --------- 2-phase pipelined GEMM: 128M x 256N, BK=64, triple-buffer -------
// C[m][n] = sum_k A[m][k]*Bw[n][k]; A,Bw bf16.  512 thr = 8 waves (2M x 4N),
// per-wave 64x64 (acc[4][4]).  3 x 48KB LDS (144 KiB).  Per K-tile: 2 phases
// of {8 ds_read || 3 stage units -> lgkmcnt(0)+fence -> 16 MFMA}; ONE barrier
// per K-tile (P0/P1 read the same buffer; stage targets buf (T+2)%3 whose
// readers finished before the T-1 boundary barrier).  Boundary vmcnt(6):
// tile T+2's 6 loads stay in flight — never drains in the main loop.
template <int EPI>
__global__ __launch_bounds__(512, 2) void gemm2p(const u16* __restrict__ A,
                                                 const u16* __restrict__ Bw,
                                                 void* Cout, const float* resid,
                                                 int M, int N, int K) {
  const int NK = K >> 6;
  __shared__ u16 lds[73728];          // 3 buf x (A 8192 + B 16384) u16
  const int t = threadIdx.x, lane = t & 63, w = t >> 6;
  const int wm = w >> 2, wn = w & 3;
  const int l15 = lane & 15, lg = lane >> 4;
  int bm, bn;
  tile_swz(blockIdx.x, gridDim.x, M >> 7, bm, bn);

  // staging: unit = 64 rows x 64 cols; thread t covers row t>>3, granule t&7,
  // global source granule pre-swizzled by row&7 (involution, r5-verified).
  const int r64 = t >> 3;
  const int gsrc = ((t & 7) ^ (r64 & 7)) * 8;
  const u16* Asrc[2];
#pragma unroll
  for (int u = 0; u < 2; ++u)
    Asrc[u] = A + (size_t)(bm * 128 + u * 64 + r64) * K + gsrc;
  const u16* Bsrc[4];
#pragma unroll
  for (int u = 0; u < 4; ++u)
    Bsrc[u] = Bw + (size_t)(bn * 256 + u * 64 + r64) * K + gsrc;
  const int d0 = t * 8;

#define STG_A2(buf, u, kt)                                                     \
  GLOBAL_LOAD_LDS16(Asrc[u] + (kt) * 64, &lds[(buf) * 24576 + (u) * 4096 + d0])
#define STG_B2(buf, u, kt)                                                     \
  GLOBAL_LOAD_LDS16(Bsrc[u] + (kt) * 64,                                       \
                    &lds[(buf) * 24576 + 8192 + (u) * 4096 + d0])

  const int swz0 = (lg ^ (l15 & 7)) * 8;
  const int swz1 = ((4 + lg) ^ (l15 & 7)) * 8;
  const int abase = wm * 4096 + l15 * 64;          // + mf*1024 + swz
  const int bbase = 8192 + wn * 4096 + l15 * 64;   // + nf*1024 + swz

  f32x4 acc[4][4] = {};
  bf16x8 af[4], bfr[4];

  // prologue: tiles 0 and 1 fully staged (12 loads)
  STG_A2(0, 0, 0); STG_A2(0, 1, 0);
  STG_B2(0, 0, 0); STG_B2(0, 1, 0); STG_B2(0, 2, 0); STG_B2(0, 3, 0);
  STG_A2(1, 0, 1); STG_A2(1, 1, 1);
  STG_B2(1, 0, 1); STG_B2(1, 1, 1); STG_B2(1, 2, 1); STG_B2(1, 3, 1);
  asm volatile("s_waitcnt vmcnt(6)" ::: "memory");   // tile0 landed
  __builtin_amdgcn_s_barrier();

  for (int T = 0; T < NK; ++T) {
    const int bb = (T % 3) * 24576;
    const int nb = (T + 2) % 3;
    // ---------------- P0: ks=0 ----------------
#pragma unroll
    for (int i = 0; i < 4; ++i)
      af[i] = *(const bf16x8*)&lds[bb + abase + i * 1024 + swz0];
#pragma unroll
    for (int n = 0; n < 4; ++n)
      bfr[n] = *(const bf16x8*)&lds[bb + bbase + n * 1024 + swz0];
    if (T < NK - 2) { STG_A2(nb, 0, T + 2); STG_A2(nb, 1, T + 2); STG_B2(nb, 0, T + 2); }
    PHASE_TAIL();
#pragma unroll
    for (int i = 0; i < 4; ++i)
#pragma unroll
      for (int n = 0; n < 4; ++n)
        acc[i][n] = __builtin_amdgcn_mfma_f32_16x16x32_bf16(af[i], bfr[n], acc[i][n], 0, 0, 0);
    __builtin_amdgcn_s_setprio(0);
    // ---------------- P1: ks=1 (same buffer — no barrier needed) ----------
#pragma unroll
    for (int i = 0; i < 4; ++i)
      af[i] = *(const bf16x8*)&lds[bb + abase + i * 1024 + swz1];
#pragma unroll
    for (int n = 0; n < 4; ++n)
      bfr[n] = *(const bf16x8*)&lds[bb + bbase + n * 1024 + swz1];
    if (T < NK - 2) { STG_B2(nb, 1, T + 2); STG_B2(nb, 2, T + 2); STG_B2(nb, 3, T + 2); }
    PHASE_TAIL();
#pragma unroll
    for (int i = 0; i < 4; ++i)
#pragma unroll
      for (int n = 0; n < 4; ++n)
        acc[i][n] = __builtin_amdgcn_mfma_f32_16x16x32_bf16(af[i], bfr[n], acc[i][n], 0, 0, 0);
    __builtin_amdgcn_s_setprio(0);
    // boundary: ensure tile T+1 landed; keep T+2's 6 loads in flight
    if (T < NK - 1) {
      if (T < NK - 2) asm volatile("s_waitcnt vmcnt(6)" ::: "memory");
      else            asm volatile("s_waitcnt vmcnt(0)" ::: "memory");
      __builtin_amdgcn_s_barrier();
    }
  }
#undef STG_A2
#undef STG_B2

#pragma unroll
  for (int mf = 0; mf < 4; ++mf)
#pragma unroll
    for (int nf = 0; nf < 4; ++nf)
#pragma unroll
      for (int r = 0; r < 4; ++r) {
        int row = bm * 128 + wm * 64 + mf * 16 + lg * 4 + r;
        int col = bn * 256 + wn * 64 + nf * 16 + l15;
        size_t idx = (size_t)row * N + col;
        if (EPI == 0)
          ((u16*)Cout)[idx] = f2bf(acc[mf][nf][r]);
        else
          ((float*)Cout)[idx] = resid[idx] + acc[mf][nf][r];
      }
}

// ---------------- fused gate/up: 4-phase pipelined 256x(128g+128u) ---------
// (round-7 verified schedule: single barrier per phase, after the MFMAs)
__global__ __launch_bounds__(512, 2) void gu256(const u16* __restrict__ A,
                                                const u16* __restrict__ Wg,
                                                const u16* __restrict__ Wu,
                                                u16* __restrict__ G) {
  constexpr int KD = 2048, NK = 32;
  __shared__ u16 lds[65536];          // 2 buf x (A 16384 + B 16384) u16
  const int t = threadIdx.x, lane = t & 63, w = t >> 6;
  const int wm = w >> 2, wn = w & 3;
  const int l15 = lane & 15, lg = lane >> 4;
  int bm, bn;
  tile_swz(blockIdx.x, gridDim.x, 16, bm, bn);   // grid 704 = 16(M) x 44(N)

  const int l8 = lane >> 3, g8 = lane & 7;
  const int gsrc = (g8 ^ l8) * 8;                 // u16 offset
  const u16* Asrc[2][2];
#pragma unroll
  for (int ha = 0; ha < 2; ++ha)
#pragma unroll
    for (int c = 0; c < 2; ++c)
      Asrc[ha][c] = A + (size_t)(bm * 256 + ha * 128 + w * 16 + c * 8 + l8) * KD + gsrc;
  const u16* Wsel = ((w >> 1) & 1) ? Wu : Wg;     // uniform per wave
  const u16* Bsrc[2][2];
#pragma unroll
  for (int hb = 0; hb < 2; ++hb)
#pragma unroll
    for (int c = 0; c < 2; ++c)
      Bsrc[hb][c] = Wsel + (size_t)(bn * 128 + (hb * 2 + (w >> 2)) * 32 +
                                    (w & 1) * 16 + c * 8 + l8) * KD + gsrc;
  const int dst_wl = w * 1024 + lane * 8;

#define STG_A(buf, ha, kt) do {                                                \
    GLOBAL_LOAD_LDS16(Asrc[ha][0] + (kt) * 64,                                 \
                      &lds[(buf) * 32768 + (ha) * 8192 + dst_wl]);             \
    GLOBAL_LOAD_LDS16(Asrc[ha][1] + (kt) * 64,                                 \
                      &lds[(buf) * 32768 + (ha) * 8192 + dst_wl + 512]); } while (0)
#define STG_B(buf, hb, kt) do {                                                \
    GLOBAL_LOAD_LDS16(Bsrc[hb][0] + (kt) * 64,                                 \
                      &lds[(buf) * 32768 + 16384 + (hb) * 8192 + dst_wl]);     \
    GLOBAL_LOAD_LDS16(Bsrc[hb][1] + (kt) * 64,                                 \
                      &lds[(buf) * 32768 + 16384 + (hb) * 8192 + dst_wl + 512]); } while (0)

  const int swz0 = (lg ^ (l15 & 7)) * 8;
  const int swz1 = ((4 + lg) ^ (l15 & 7)) * 8;
  const int abase = (wm * 128 + l15) * 64;
  const int bbase = 16384 + (wn * 64 + l15) * 64;

  f32x4 acc[8][4] = {};
  bf16x8 af[4], bf0[4], bf1[4];

  STG_A(0, 0, 0); STG_A(0, 1, 0);
  STG_B(0, 0, 0); STG_B(0, 1, 0);
  STG_B(1, 0, 1); STG_B(1, 1, 1);
  asm volatile("s_waitcnt vmcnt(4)" ::: "memory");
  __builtin_amdgcn_s_barrier();

  for (int T = 0; T < NK; ++T) {
    const int bb = (T & 1) * 32768;
    const int nbuf = (T + 1) & 1, cbuf = T & 1;
    // P0
#pragma unroll
    for (int i = 0; i < 4; ++i)
      af[i] = *(const bf16x8*)&lds[bb + abase + i * 1024 + swz0];
#pragma unroll
    for (int n = 0; n < 4; ++n)
      bf0[n] = *(const bf16x8*)&lds[bb + bbase + n * 1024 + swz0];
    if (T < NK - 1) STG_A(nbuf, 0, T + 1);
    PHASE_TAIL();
#pragma unroll
    for (int i = 0; i < 4; ++i)
#pragma unroll
      for (int n = 0; n < 4; ++n)
        acc[i][n] = __builtin_amdgcn_mfma_f32_16x16x32_bf16(af[i], bf0[n], acc[i][n], 0, 0, 0);
    __builtin_amdgcn_s_setprio(0);
    __builtin_amdgcn_s_barrier();
    // P1
#pragma unroll
    for (int i = 0; i < 4; ++i)
      af[i] = *(const bf16x8*)&lds[bb + abase + i * 1024 + swz1];
#pragma unroll
    for (int n = 0; n < 4; ++n)
      bf1[n] = *(const bf16x8*)&lds[bb + bbase + n * 1024 + swz1];
    if (T < NK - 1) STG_A(nbuf, 1, T + 1);
    PHASE_TAIL();
#pragma unroll
    for (int i = 0; i < 4; ++i)
#pragma unroll
      for (int n = 0; n < 4; ++n)
        acc[i][n] = __builtin_amdgcn_mfma_f32_16x16x32_bf16(af[i], bf1[n], acc[i][n], 0, 0, 0);
    __builtin_amdgcn_s_setprio(0);
    __builtin_amdgcn_s_barrier();
    // P2
#pragma unroll
    for (int i = 0; i < 4; ++i)
      af[i] = *(const bf16x8*)&lds[bb + abase + (4 + i) * 1024 + swz0];
    if (T < NK - 2) STG_B(cbuf, 0, T + 2);
    PHASE_TAIL();
#pragma unroll
    for (int i = 0; i < 4; ++i)
#pragma unroll
      for (int n = 0; n < 4; ++n)
        acc[4 + i][n] = __builtin_amdgcn_mfma_f32_16x16x32_bf16(af[i], bf0[n], acc[4 + i][n], 0, 0, 0);
    __builtin_amdgcn_s_setprio(0);
    __builtin_amdgcn_s_barrier();
    // P3
#pragma unroll
    for (int i = 0; i < 4; ++i)
      af[i] = *(const bf16x8*)&lds[bb + abase + (4 + i) * 1024 + swz1];
    if (T < NK - 2) STG_B(cbuf, 1, T + 2);
    PHASE_TAIL();
#pragma unroll
    for (int i = 0; i < 4; ++i)
#pragma unroll
      for (int n = 0; n < 4; ++n)
        acc[4 + i][n] = __builtin_amdgcn_mfma_f32_16x16x32_bf16(af[i], bf1[n], acc[4 + i][n], 0, 0, 0);
    __builtin_amdgcn_s_setprio(0);
    if (T < NK - 2) asm volatile("s_waitcnt vmcnt(4)" ::: "memory");
    else            asm volatile("s_waitcnt vmcnt(0)" ::: "memory");
    __builtin_amdgcn_s_barrier();
  }
#undef STG_A
#undef STG_B

  const size_t grow0 = (size_t)(bm * 256 + wm * 128 + lg * 4);
  const int gcol0 = bn * 128 + wn * 32 + l15;
#pragma unroll
  for (int mf = 0; mf < 8; ++mf)
#pragma unroll
    for (int p = 0; p < 2; ++p)
#pragma unroll
      for (int r = 0; r < 4; ++r) {
        float gg = acc[mf][p][r], uu = acc[mf][p + 2][r];
        float sg = gg / (1.0f + __expf(-gg));
        G[(grow0 + mf * 16 + r) * 5632 + gcol0 + p * 16] = f2bf(sg * uu);
      }
}

// ======================= fp32-weight fallback path (round-1, verified) =====
template <int EPI>
__global__ __launch_bounds__(256) void gemm_bt(const u16* __restrict__ A,
                                               const float* __restrict__ Bw,
                                               void* Cout, const float* resid,
                                               int M, int N, int K) {
  __shared__ u16 sA[128 * 32];
  __shared__ u16 sB[128 * 40];
  const int t = threadIdx.x, lane = t & 63, w = t >> 6;
  const int l15 = lane & 15, lg = lane >> 4;
  const int tn = N >> 7;
  const int bm = blockIdx.x / tn, bn = blockIdx.x % tn;
  const int wr = (w >> 1) << 6, wc = (w & 1) << 6;

  const u16* Ag  = A + (size_t)(bm * 128 + (t >> 2)) * K + (t & 3) * 8;
  const u16* Ag2 = Ag + (size_t)64 * K;
  const float* Bg  = Bw + (size_t)(bn * 128 + (t >> 2)) * K + (t & 3) * 8;
  const float* Bg2 = Bg + (size_t)64 * K;
  u16* sBp  = &sB[(t >> 2) * 40 + (t & 3) * 8];
  u16* sBp2 = sBp + 64 * 40;

  f32x4 acc[4][4] = {};

  for (int kt = 0; kt < K; kt += 32) {
    float4 b0 = *(const float4*)(Bg + kt);
    float4 b1 = *(const float4*)(Bg + kt + 4);
    float4 c0 = *(const float4*)(Bg2 + kt);
    float4 c1 = *(const float4*)(Bg2 + kt + 4);
    GLOBAL_LOAD_LDS16(Ag + kt, &sA[t * 8]);
    GLOBAL_LOAD_LDS16(Ag2 + kt, &sA[64 * 32 + t * 8]);
    u16x8 bs;
    bs[0] = f2bf(b0.x); bs[1] = f2bf(b0.y); bs[2] = f2bf(b0.z); bs[3] = f2bf(b0.w);
    bs[4] = f2bf(b1.x); bs[5] = f2bf(b1.y); bs[6] = f2bf(b1.z); bs[7] = f2bf(b1.w);
    *(u16x8*)sBp = bs;
    bs[0] = f2bf(c0.x); bs[1] = f2bf(c0.y); bs[2] = f2bf(c0.z); bs[3] = f2bf(c0.w);
    bs[4] = f2bf(c1.x); bs[5] = f2bf(c1.y); bs[6] = f2bf(c1.z); bs[7] = f2bf(c1.w);
    *(u16x8*)sBp2 = bs;
    __syncthreads();
    bf16x8 af[4], bfr[4];
#pragma unroll
    for (int m = 0; m < 4; ++m)
      af[m] = *(const bf16x8*)&sA[(wr + m * 16 + l15) * 32 + lg * 8];
#pragma unroll
    for (int n = 0; n < 4; ++n)
      bfr[n] = *(const bf16x8*)&sB[(wc + n * 16 + l15) * 40 + lg * 8];
#pragma unroll
    for (int m = 0; m < 4; ++m)
#pragma unroll
      for (int n = 0; n < 4; ++n)
        acc[m][n] = __builtin_amdgcn_mfma_f32_16x16x32_bf16(af[m], bfr[n], acc[m][n], 0, 0, 0);
    __syncthreads();
  }
#pragma unroll
  for (int m = 0; m < 4; ++m)
#pragma unroll
    for (int n = 0; n < 4; ++n)
#pragma unroll
      for (int r = 0; r < 4; ++r) {
        int row = bm * 128 + wr + m * 16 + lg * 4 + r;
        int col = bn * 128 + wc + n * 16 + l15;
        size_t idx = (size_t)row * N + col;
        if (EPI == 0)
          ((u16*)Cout)[idx] = f2bf(acc[m][n][r]);
        else
          ((float*)Cout)[idx] = resid[idx] + acc[m][n][r];
      }
}

__global__ __launch_bounds__(512) void gemm_gateup(const u16* __restrict__ A,
                                                   const float* __restrict__ Wg,
                                                   const float* __restrict__ Wu,
                                                   u16* __restrict__ G) {
  constexpr int N = 5632, K = 2048;
  __shared__ u16 sA[128 * 32];
  __shared__ u16 sB1[128 * 40];
  __shared__ u16 sB2[128 * 40];
  const int t = threadIdx.x, lane = t & 63, w = t >> 6;
  const int l15 = lane & 15, lg = lane >> 4;
  const int bm = blockIdx.x / 44, bn = blockIdx.x % 44;
  const int wr = (w >> 2) << 6, wc = (w & 3) << 5;

  const u16* Ag = A + (size_t)(bm * 128 + (t >> 2)) * K + (t & 3) * 8;
  const float* Bg1 = Wg + (size_t)(bn * 128 + (t >> 2)) * K + (t & 3) * 8;
  const float* Bg2 = Wu + (size_t)(bn * 128 + (t >> 2)) * K + (t & 3) * 8;
  const int sboff = (t >> 2) * 40 + (t & 3) * 8;

  f32x4 acc1[4][2] = {};
  f32x4 acc2[4][2] = {};

  for (int kt = 0; kt < K; kt += 32) {
    float4 g0 = *(const float4*)(Bg1 + kt);
    float4 g1 = *(const float4*)(Bg1 + kt + 4);
    float4 u0 = *(const float4*)(Bg2 + kt);
    float4 u1 = *(const float4*)(Bg2 + kt + 4);
    GLOBAL_LOAD_LDS16(Ag + kt, &sA[t * 8]);
    u16x8 bs;
    bs[0] = f2bf(g0.x); bs[1] = f2bf(g0.y); bs[2] = f2bf(g0.z); bs[3] = f2bf(g0.w);
    bs[4] = f2bf(g1.x); bs[5] = f2bf(g1.y); bs[6] = f2bf(g1.z); bs[7] = f2bf(g1.w);
    *(u16x8*)&sB1[sboff] = bs;
    bs[0] = f2bf(u0.x); bs[1] = f2bf(u0.y); bs[2] = f2bf(u0.z); bs[3] = f2bf(u0.w);
    bs[4] = f2bf(u1.x); bs[5] = f2bf(u1.y); bs[6] = f2bf(u1.z); bs[7] = f2bf(u1.w);
    *(u16x8*)&sB2[sboff] = bs;
    __syncthreads();
    bf16x8 af[4], b1f[2], b2f[2];
#pragma unroll
    for (int m = 0; m < 4; ++m)
      af[m] = *(const bf16x8*)&sA[(wr + m * 16 + l15) * 32 + lg * 8];
#pragma unroll
    for (int n = 0; n < 2; ++n) {
      b1f[n] = *(const bf16x8*)&sB1[(wc + n * 16 + l15) * 40 + lg * 8];
      b2f[n] = *(const bf16x8*)&sB2[(wc + n * 16 + l15) * 40 + lg * 8];
    }
#pragma unroll
    for (int m = 0; m < 4; ++m)
#pragma unroll
      for (int n = 0; n < 2; ++n) {
        acc1[m][n] = __builtin_amdgcn_mfma_f32_16x16x32_bf16(af[m], b1f[n], acc1[m][n], 0, 0, 0);
        acc2[m][n] = __builtin_amdgcn_mfma_f32_16x16x32_bf16(af[m], b2f[n], acc2[m][n], 0, 0, 0);
      }
    __syncthreads();
  }
#pragma unroll
  for (int m = 0; m < 4; ++m)
#pragma unroll
    for (int n = 0; n < 2; ++n)
#pragma unroll
      for (int r = 0; r < 4; ++r) {
        int row = bm * 128 + wr + m * 16 + lg * 4 + r;
        int col = bn * 128 + wc + n * 16 + l15;
        float ga = acc1[m][n][r], uu = acc2[m][n][r];
        float sg = ga / (1.0f + __expf(-ga));
        G[(size_t)row * N + col] = f2bf(sg * uu);
      }
}

// -------------------------------------------------------------- attention ---
__global__ __launch_bounds__(256) void attn_k(const u16* __restrict__ Q,
                                              const u16* __restrict__ K,
                                              const u16* __restrict__ V,
                                              u16* __restrict__ O,
                                              int qstr, int kvstr) {
  const int lane = threadIdx.x & 63;
  const int wid = blockIdx.x * 4 + (threadIdx.x >> 6);
  const int qt = wid & 127;
  const int h = (wid >> 7) & 15;
  const int b = wid >> 11;
  const int q0 = qt << 4;
  const int kvh = h >> 2;
  const int l15 = lane & 15, lg = lane >> 4;

  bf16x8 qf[4];
  {
    const u16* qp = Q + (size_t)((b << 11) + q0 + l15) * qstr + h * 128 + lg * 8;
#pragma unroll
    for (int ds = 0; ds < 4; ++ds) qf[ds] = *(const bf16x8*)(qp + ds * 32);
  }
  float m_run = -1e30f, l_run = 0.0f;
  f32x4 oacc[8];
#pragma unroll
  for (int db = 0; db < 8; ++db) oacc[db] = f32x4{0.f, 0.f, 0.f, 0.f};

  int lo = q0 - 511;
  if (lo < 0) lo = 0;
  for (int kb = (lo & ~15); kb <= q0; kb += 16) {
    f32x4 st = {0.f, 0.f, 0.f, 0.f};
    const u16* kp = K + (size_t)((b << 11) + kb + l15) * kvstr + kvh * 128 + lg * 8;
#pragma unroll
    for (int ds = 0; ds < 4; ++ds)
      st = __builtin_amdgcn_mfma_f32_16x16x32_bf16(*(const bf16x8*)(kp + ds * 32),
                                                   qf[ds], st, 0, 0, 0);
    const int qpos = q0 + l15;
    float pe[4];
    float tmax = -1e30f;
#pragma unroll
    for (int r = 0; r < 4; ++r) {
      int j = kb + lg * 4 + r;
      int d = qpos - j;
      bool ok = (d >= 0) && (d < 512);
      pe[r] = ok ? st[r] * 0.08838834764831845f : -1e30f;
      tmax = fmaxf(tmax, pe[r]);
    }
    tmax = fmaxf(tmax, __shfl_xor(tmax, 16));
    tmax = fmaxf(tmax, __shfl_xor(tmax, 32));
    float m_new = fmaxf(m_run, tmax);
    float corr = __expf(m_run - m_new);
    float psum = 0.0f;
#pragma unroll
    for (int r = 0; r < 4; ++r) {
      float e = (pe[r] > -1e29f) ? __expf(pe[r] - m_new) : 0.0f;
      pe[r] = e;
      psum += e;
    }
    psum += __shfl_xor(psum, 16);
    psum += __shfl_xor(psum, 32);
    l_run = l_run * corr + psum;
    m_run = m_new;

    f16x4 pf;
#pragma unroll
    for (int r = 0; r < 4; ++r) pf[r] = (_Float16)pe[r];

    float f0 = __shfl(corr, lg * 4 + 0);
    float f1 = __shfl(corr, lg * 4 + 1);
    float f2 = __shfl(corr, lg * 4 + 2);
    float f3 = __shfl(corr, lg * 4 + 3);
    const u16* vp = V + (size_t)((b << 11) + kb + lg * 4) * kvstr + kvh * 128 + l15;
#pragma unroll
    for (int db = 0; db < 8; ++db) {
      oacc[db][0] *= f0; oacc[db][1] *= f1; oacc[db][2] *= f2; oacc[db][3] *= f3;
      f16x4 vf;
#pragma unroll
      for (int e = 0; e < 4; ++e)
        vf[e] = (_Float16)bf2f(vp[(size_t)e * kvstr + db * 16]);
      oacc[db] = __builtin_amdgcn_mfma_f32_16x16x16f16(pf, vf, oacc[db], 0, 0, 0);
    }
  }
  float inv = 1.0f / l_run;
  float g0 = __shfl(inv, lg * 4 + 0);
  float g1 = __shfl(inv, lg * 4 + 1);
  float g2 = __shfl(inv, lg * 4 + 2);
  float g3 = __shfl(inv, lg * 4 + 3);
  u16* op = O + (size_t)((b << 11) + q0 + lg * 4) * 2048 + h * 128 + l15;
#pragma unroll
  for (int db = 0; db < 8; ++db) {
    op[0 * 2048 + db * 16] = f2bf(oacc[db][0] * g0);
    op[1 * 2048 + db * 16] = f2bf(oacc[db][1] * g1);
    op[2 * 2048 + db * 16] = f2bf(oacc[db][2] * g2);
    op[3 * 2048 + db * 16] = f2bf(oacc[db][3] * g3);
  }
}

// ----------------------------------------------------------------- launch ---
extern "C" void kernel_launch(void* const* d_in, const int* in_sizes, int n_in,
                              void* d_out, int out_size, void* d_ws, size_t ws_size,
                              hipStream_t stream) {
  const float* x    = (const float*)d_in[0];
  const float* cosp = (const float*)d_in[1];
  const float* sinp = (const float*)d_in[2];
  const float* ln1  = (const float*)d_in[3];
  const float* ln2  = (const float*)d_in[4];
  const float* wq   = (const float*)d_in[5];
  const float* wk   = (const float*)d_in[6];
  const float* wv   = (const float*)d_in[7];
  const float* wo   = (const float*)d_in[8];
  const float* wg   = (const float*)d_in[9];
  const float* wu   = (const float*)d_in[10];
  const float* wd   = (const float*)d_in[11];
  float* out = (float*)d_out;

  const size_t SZ_HQ  = 8388608;   // 4096*2048
  const size_t SZ_KV  = 2097152;   // 4096*512
  const size_t SZ_QKV = 12582912;  // 4096*3072
  const size_t SZ_G   = 23068672;  // 4096*5632
  const size_t SZ_WB  = 23068672;  // max bf16 weight residency (wg+wu)
  const size_t need_old = (SZ_HQ * 3 + SZ_KV * 2 + SZ_G) * 2;            // 100 MiB
  const size_t need_new = (SZ_HQ * 2 + SZ_QKV + SZ_G + SZ_WB) * 2;       // 144 MiB
  if (ws_size < need_old) return;  // clean fail rather than OOB

  if (ws_size >= need_new) {
    // ---- bf16-weight pipelined path ----
    u16* h   = (u16*)d_ws;
    u16* qkv = h + SZ_HQ;               // [4096][3072]: q | k | v
    u16* at  = qkv + SZ_QKV;
    u16* g   = at + SZ_HQ;
    u16* wb  = g + SZ_G;                // reused weight slab
    u16* wqb = wb;                      // 3072x2048 combined qkv weights
    u16* wob = wb;                      // reused after QKV
    u16* wgb = wb;                      // reused: gate (wub contiguous)
    u16* wdb = wb;                      // reused: down

    rmsnorm_k<<<4096, 256, 0, stream>>>(x, ln1, h);
    cvt3_k<<<2048, 256, 0, stream>>>(wq, wk, wv, wqb, 4194304, 1048576, 1048576);
    gemm2p<0><<<384, 512, 0, stream>>>(h, wqb, qkv, nullptr, 4096, 3072, 2048);
    rope_qkv<<<20480, 256, 0, stream>>>(qkv, cosp, sinp);
    attn_k<<<1024, 256, 0, stream>>>(qkv, qkv + 2048, qkv + 2560, at, 3072, 3072);
    cvt_k<<<2048, 256, 0, stream>>>(wo, wob, 4194304);
    gemm2p<1><<<256, 512, 0, stream>>>(at, wob, d_out, x, 4096, 2048, 2048);
    rmsnorm_k<<<4096, 256, 0, stream>>>(out, ln2, h);
    cvt3_k<<<2048, 256, 0, stream>>>(wg, wu, wu, wgb, 11534336, 11534336, 0);
    gu256<<<704, 512, 0, stream>>>(h, wgb, wgb + 11534336, g);
    cvt_k<<<2048, 256, 0, stream>>>(wd, wdb, 11534336);
    gemm2p<1><<<256, 512, 0, stream>>>(g, wdb, d_out, out, 4096, 2048, 5632);
  } else {
    // ---- fp32-weight fallback (round-1 verified) ----
    u16* h  = (u16*)d_ws;
    u16* q  = h + SZ_HQ;
    u16* kk = q + SZ_HQ;
    u16* vv = kk + SZ_KV;
    u16* at = vv + SZ_KV;
    u16* g  = at + SZ_HQ;

    rmsnorm_k<<<4096, 256, 0, stream>>>(x, ln1, h);
    gemm_bt<0><<<512, 256, 0, stream>>>(h, wq, q,  nullptr, 4096, 2048, 2048);
    gemm_bt<0><<<128, 256, 0, stream>>>(h, wk, kk, nullptr, 4096, 512, 2048);
    gemm_bt<0><<<128, 256, 0, stream>>>(h, wv, vv, nullptr, 4096, 512, 2048);
    rope_k<<<16384, 256, 0, stream>>>(q, cosp, sinp, 16, 4194304);
    rope_k<<<4096, 256, 0, stream>>>(kk, cosp, sinp, 4, 1048576);
    attn_k<<<1024, 256, 0, stream>>>(q, kk, vv, at, 2048, 512);
    gemm_bt<1><<<512, 256, 0, stream>>>(at, wo, d_out, x, 4096, 2048, 2048);
    rmsnorm_k<<<4096, 256, 0, stream>>>(out, ln2, h);
    gemm_gateup<<<1408, 512, 0, stream>>>(h, wg, wu, g);
    gemm_bt<1><<<512, 256, 0, stream>>>(g, wd, d_out, out, 4096, 2048, 5632);
  }
}